// Round 11
// baseline (134.117 us; speedup 1.0000x reference)
//
#include <hip/hip_runtime.h>

#define BATCH 128
#define M 259
#define D 512
#define T 256
#define NM (BATCH * M)          // 33152
#define OUTHALF (BATCH * T * D)

typedef __bf16 bf16;
typedef __bf16 bf16x4 __attribute__((ext_vector_type(4)));
typedef __bf16 bf16x8 __attribute__((ext_vector_type(8)));
typedef float f32x4 __attribute__((ext_vector_type(4)));

// ws layout (floats): na[NM] | nb[NM] | wcol[NM] | wrow[NM]
// fast path appends (bf16): a_bf[NM*D] | b_bf[NM*D]

// ---------- Kernel P: fp32->bf16 convert + norms + zero accumulators -------
// (r7-proven; ~34 us: streams inputs once, writes bf16 mirror)
__global__ void k_prep(const float* __restrict__ x1, const float* __restrict__ x2,
                       float* __restrict__ ws, bf16* __restrict__ abf,
                       bf16* __restrict__ bbf) {
    int row  = blockIdx.x * 4 + (threadIdx.x >> 6);
    int lane = threadIdx.x & 63;
    if (row >= NM) return;
    const float4* p1 = (const float4*)(x1 + (size_t)row * D);
    const float4* p2 = (const float4*)(x2 + (size_t)row * D);
    float4 a0 = p1[lane], a1 = p1[lane + 64];
    float4 b0 = p2[lane], b1 = p2[lane + 64];
    float s1 = a0.x * a0.x + a0.y * a0.y + a0.z * a0.z + a0.w * a0.w
             + a1.x * a1.x + a1.y * a1.y + a1.z * a1.z + a1.w * a1.w;
    float s2 = b0.x * b0.x + b0.y * b0.y + b0.z * b0.z + b0.w * b0.w
             + b1.x * b1.x + b1.y * b1.y + b1.z * b1.z + b1.w * b1.w;
    bf16* ar = abf + (size_t)row * D;
    bf16* br = bbf + (size_t)row * D;
    *(bf16x4*)(ar + 4 * lane)       = bf16x4{ (bf16)a0.x, (bf16)a0.y, (bf16)a0.z, (bf16)a0.w };
    *(bf16x4*)(ar + 256 + 4 * lane) = bf16x4{ (bf16)a1.x, (bf16)a1.y, (bf16)a1.z, (bf16)a1.w };
    *(bf16x4*)(br + 4 * lane)       = bf16x4{ (bf16)b0.x, (bf16)b0.y, (bf16)b0.z, (bf16)b0.w };
    *(bf16x4*)(br + 256 + 4 * lane) = bf16x4{ (bf16)b1.x, (bf16)b1.y, (bf16)b1.z, (bf16)b1.w };
#pragma unroll
    for (int off = 32; off > 0; off >>= 1) {
        s1 += __shfl_xor(s1, off);
        s2 += __shfl_xor(s2, off);
    }
    if (lane == 0) {
        ws[row]          = s1;
        ws[NM + row]     = s2;
        ws[2 * NM + row] = 0.f;
        ws[3 * NM + row] = 0.f;
    }
}

// ---------- Kernel 2 (fast): r2 structure verbatim, bf16-source staging ----
#define BT 96
#define BK 64
#define NTL 3

__launch_bounds__(256)
__global__ void k_pairs_bf(const bf16* __restrict__ gA0, const bf16* __restrict__ gB0,
                           float* __restrict__ ws) {
    __shared__ __align__(16) bf16 As[BT * BK];   // 12 KB
    __shared__ __align__(16) bf16 Bs[BT * BK];   // 12 KB

    int s   = blockIdx.x;                 // 1152 = 8 * 144, bijective XCD swizzle
    int bid = (s & 7) * 144 + (s >> 3);
    int b   = bid / 9;
    int ti  = (bid % 9) / 3;
    int tj  = bid % 3;
    int i0  = ti * BT, j0 = tj * BT;

    int t    = threadIdx.x;
    int lane = t & 63;
    int w    = t >> 6;
    int wm   = w >> 1, wn = w & 1;
    int iw   = i0 + wm * 48;
    int jw   = j0 + wn * 48;

    const bf16* gA = gA0 + (size_t)b * M * D;
    const bf16* gB = gB0 + (size_t)b * M * D;

    // staging: 3 passes/matrix; thread covers row (t>>3)+32p, slot t&7 (16B)
    int srow = t >> 3;                    // 0..31
    int slot = t & 7;
    const bf16* pa[3];
    const bf16* pb[3];
    int wro[3];
    int sx = (slot ^ (srow & 7)) << 3;    // write swizzle (row&7 invariant mod 32)
#pragma unroll
    for (int p = 0; p < 3; ++p) {
        int row = srow + 32 * p;          // 0..95
        int ra = min(i0 + row, M - 1);
        int rb = min(j0 + row, M - 1);
        pa[p] = gA + (size_t)ra * D + slot * 8;
        pb[p] = gB + (size_t)rb * D + slot * 8;
        wro[p] = row * BK + sx;
    }

    // fragment read offsets (proven swizzle-matched formula)
    int a_off[3][2], b_off[3][2];
#pragma unroll
    for (int fm = 0; fm < 3; ++fm) {
        int rowa = wm * 48 + fm * 16 + (lane & 15);
        int rowb = wn * 48 + fm * 16 + (lane & 15);
#pragma unroll
        for (int kk = 0; kk < 2; ++kk) {
            int sl = kk * 4 + (lane >> 4);
            a_off[fm][kk] = rowa * BK + ((sl ^ (rowa & 7)) << 3);
            b_off[fm][kk] = rowb * BK + ((sl ^ (rowb & 7)) << 3);
        }
    }

    f32x4 acc[3][3];
#pragma unroll
    for (int fm = 0; fm < 3; ++fm)
#pragma unroll
        for (int fn = 0; fn < 3; ++fn) acc[fm][fn] = (f32x4)0.f;

    for (int k0 = 0; k0 < D; k0 += BK) {
        bf16x8 va[3], vb[3];
#pragma unroll
        for (int p = 0; p < 3; ++p) {
            va[p] = *(const bf16x8*)(pa[p] + k0);
            vb[p] = *(const bf16x8*)(pb[p] + k0);
        }
        __syncthreads();
#pragma unroll
        for (int p = 0; p < 3; ++p) {
            *(bf16x8*)&As[wro[p]] = va[p];
            *(bf16x8*)&Bs[wro[p]] = vb[p];
        }
        __syncthreads();
#pragma unroll
        for (int kk = 0; kk < 2; ++kk) {
            bf16x8 af[3], bfr[3];
#pragma unroll
            for (int fm = 0; fm < 3; ++fm) af[fm]  = *(const bf16x8*)&As[a_off[fm][kk]];
#pragma unroll
            for (int fn = 0; fn < 3; ++fn) bfr[fn] = *(const bf16x8*)&Bs[b_off[fn][kk]];
#pragma unroll
            for (int fm = 0; fm < 3; ++fm)
#pragma unroll
                for (int fn = 0; fn < 3; ++fn)
                    acc[fm][fn] = __builtin_amdgcn_mfma_f32_16x16x32_bf16(
                        af[fm], bfr[fn], acc[fm][fn], 0, 0, 0);
        }
    }

    // epilogue (r2 verbatim)
    int b_off_w = b * M;
    float na_[3][4], nb_[3];
#pragma unroll
    for (int fm = 0; fm < 3; ++fm)
#pragma unroll
        for (int r = 0; r < 4; ++r) {
            int i = iw + fm * 16 + (lane >> 4) * 4 + r;
            na_[fm][r] = (i < M) ? ws[b_off_w + i] : 0.f;
        }
#pragma unroll
    for (int fn = 0; fn < 3; ++fn) {
        int j = jw + fn * 16 + (lane & 15);
        nb_[fn] = (j < M) ? ws[NM + b_off_w + j] : 0.f;
    }

    float rs[3][4], cs[3];
#pragma unroll
    for (int fm = 0; fm < 3; ++fm)
#pragma unroll
        for (int r = 0; r < 4; ++r) rs[fm][r] = 0.f;
#pragma unroll
    for (int fn = 0; fn < 3; ++fn) cs[fn] = 0.f;

#pragma unroll
    for (int fm = 0; fm < 3; ++fm) {
#pragma unroll
        for (int fn = 0; fn < 3; ++fn) {
#pragma unroll
            for (int r = 0; r < 4; ++r) {
                int i = iw + fm * 16 + (lane >> 4) * 4 + r;
                int j = jw + fn * 16 + (lane & 15);
                float av = 0.f;
                if (i < M && j < M) {
                    float sq   = na_[fm][r] + nb_[fn] - 2.f * acc[fm][fn][r];
                    float dist = sqrtf(fmaxf(sq, 0.f));
                    av = 1.f / (1.f + dist);
                }
                rs[fm][r] += av;
                cs[fn]    += av;
            }
        }
    }

#pragma unroll
    for (int fm = 0; fm < 3; ++fm)
#pragma unroll
        for (int r = 0; r < 4; ++r) {
            float v = rs[fm][r];
            v += __shfl_xor(v, 1); v += __shfl_xor(v, 2);
            v += __shfl_xor(v, 4); v += __shfl_xor(v, 8);
            int i = iw + fm * 16 + (lane >> 4) * 4 + r;
            if ((lane & 15) == 0 && i < M) atomicAdd(&ws[3 * NM + b_off_w + i], v);  // wrow
        }
#pragma unroll
    for (int fn = 0; fn < 3; ++fn) {
        float v = cs[fn];
        v += __shfl_xor(v, 16); v += __shfl_xor(v, 32);
        int j = jw + fn * 16 + (lane & 15);
        if ((lane >> 4) == 0 && j < M) atomicAdd(&ws[2 * NM + b_off_w + j], v);      // wcol
    }
}

// ---------- Fallback: r2 fp32 path (norms + fp32-staged pairs) -------------
__global__ void k_norms(const float* __restrict__ x1, const float* __restrict__ x2,
                        float* __restrict__ ws) {
    int row  = blockIdx.x * 4 + (threadIdx.x >> 6);
    int lane = threadIdx.x & 63;
    if (row >= NM) return;
    const float4* p1 = (const float4*)(x1 + (size_t)row * D);
    const float4* p2 = (const float4*)(x2 + (size_t)row * D);
    float s1 = 0.f, s2 = 0.f;
#pragma unroll
    for (int q = 0; q < 2; ++q) {
        float4 v = p1[lane + q * 64];
        s1 += v.x * v.x + v.y * v.y + v.z * v.z + v.w * v.w;
        float4 u = p2[lane + q * 64];
        s2 += u.x * u.x + u.y * u.y + u.z * u.z + u.w * u.w;
    }
#pragma unroll
    for (int off = 32; off > 0; off >>= 1) {
        s1 += __shfl_xor(s1, off);
        s2 += __shfl_xor(s2, off);
    }
    if (lane == 0) {
        ws[row] = s1; ws[NM + row] = s2;
        ws[2 * NM + row] = 0.f; ws[3 * NM + row] = 0.f;
    }
}

__launch_bounds__(256)
__global__ void k_pairs_fb(const float* __restrict__ x1, const float* __restrict__ x2,
                           float* __restrict__ ws) {
    __shared__ __align__(16) bf16 As[BT * BK];
    __shared__ __align__(16) bf16 Bs[BT * BK];
    int s   = blockIdx.x;
    int bid = (s & 7) * 144 + (s >> 3);
    int b   = bid / 9;
    int ti  = (bid % 9) / 3;
    int tj  = bid % 3;
    int i0  = ti * BT, j0 = tj * BT;
    int t    = threadIdx.x;
    int lane = t & 63;
    int w    = t >> 6;
    int wm   = w >> 1, wn = w & 1;
    int iw   = i0 + wm * 48, jw = j0 + wn * 48;
    const float* Ab = x1 + (size_t)b * M * D;
    const float* Bb = x2 + (size_t)b * M * D;
    const float* pa[6]; const float* pb[6];
    int c4 = (t & 15) * 4;
#pragma unroll
    for (int p = 0; p < 6; ++p) {
        int ra = min(i0 + p * 16 + (t >> 4), M - 1);
        int rb = min(j0 + p * 16 + (t >> 4), M - 1);
        pa[p] = Ab + (size_t)ra * D + c4;
        pb[p] = Bb + (size_t)rb * D + c4;
    }
    int wslot = (t & 15) >> 1, wwithin = (t & 1) * 4;
    int wr_off[6];
#pragma unroll
    for (int p = 0; p < 6; ++p) {
        int row = p * 16 + (t >> 4);
        wr_off[p] = row * BK + ((wslot ^ (row & 7)) << 3) + wwithin;
    }
    int a_off[3][2], b_off[3][2];
#pragma unroll
    for (int fm = 0; fm < 3; ++fm) {
        int rowa = wm * 48 + fm * 16 + (lane & 15);
        int rowb = wn * 48 + fm * 16 + (lane & 15);
#pragma unroll
        for (int kk = 0; kk < 2; ++kk) {
            int sl = kk * 4 + (lane >> 4);
            a_off[fm][kk] = rowa * BK + ((sl ^ (rowa & 7)) << 3);
            b_off[fm][kk] = rowb * BK + ((sl ^ (rowb & 7)) << 3);
        }
    }
    f32x4 acc[3][3];
#pragma unroll
    for (int fm = 0; fm < 3; ++fm)
#pragma unroll
        for (int fn = 0; fn < 3; ++fn) acc[fm][fn] = (f32x4)0.f;
    for (int k0 = 0; k0 < D; k0 += BK) {
        float4 va[6], vb[6];
#pragma unroll
        for (int p = 0; p < 6; ++p) {
            va[p] = *(const float4*)(pa[p] + k0);
            vb[p] = *(const float4*)(pb[p] + k0);
        }
        __syncthreads();
#pragma unroll
        for (int p = 0; p < 6; ++p) {
            *(bf16x4*)&As[wr_off[p]] = bf16x4{ (bf16)va[p].x, (bf16)va[p].y, (bf16)va[p].z, (bf16)va[p].w };
            *(bf16x4*)&Bs[wr_off[p]] = bf16x4{ (bf16)vb[p].x, (bf16)vb[p].y, (bf16)vb[p].z, (bf16)vb[p].w };
        }
        __syncthreads();
#pragma unroll
        for (int kk = 0; kk < 2; ++kk) {
            bf16x8 af[3], bfr[3];
#pragma unroll
            for (int fm = 0; fm < 3; ++fm) af[fm]  = *(const bf16x8*)&As[a_off[fm][kk]];
#pragma unroll
            for (int fn = 0; fn < 3; ++fn) bfr[fn] = *(const bf16x8*)&Bs[b_off[fn][kk]];
#pragma unroll
            for (int fm = 0; fm < 3; ++fm)
#pragma unroll
                for (int fn = 0; fn < 3; ++fn)
                    acc[fm][fn] = __builtin_amdgcn_mfma_f32_16x16x32_bf16(
                        af[fm], bfr[fn], acc[fm][fn], 0, 0, 0);
        }
    }
    int b_off_w = b * M;
    float na_[3][4], nb_[3];
#pragma unroll
    for (int fm = 0; fm < 3; ++fm)
#pragma unroll
        for (int r = 0; r < 4; ++r) {
            int i = iw + fm * 16 + (lane >> 4) * 4 + r;
            na_[fm][r] = (i < M) ? ws[b_off_w + i] : 0.f;
        }
#pragma unroll
    for (int fn = 0; fn < 3; ++fn) {
        int j = jw + fn * 16 + (lane & 15);
        nb_[fn] = (j < M) ? ws[NM + b_off_w + j] : 0.f;
    }
    float rs[3][4], cs[3];
#pragma unroll
    for (int fm = 0; fm < 3; ++fm)
#pragma unroll
        for (int r = 0; r < 4; ++r) rs[fm][r] = 0.f;
#pragma unroll
    for (int fn = 0; fn < 3; ++fn) cs[fn] = 0.f;
#pragma unroll
    for (int fm = 0; fm < 3; ++fm)
#pragma unroll
        for (int fn = 0; fn < 3; ++fn)
#pragma unroll
            for (int r = 0; r < 4; ++r) {
                int i = iw + fm * 16 + (lane >> 4) * 4 + r;
                int j = jw + fn * 16 + (lane & 15);
                float av = 0.f;
                if (i < M && j < M) {
                    float sq = na_[fm][r] + nb_[fn] - 2.f * acc[fm][fn][r];
                    av = 1.f / (1.f + sqrtf(fmaxf(sq, 0.f)));
                }
                rs[fm][r] += av; cs[fn] += av;
            }
#pragma unroll
    for (int fm = 0; fm < 3; ++fm)
#pragma unroll
        for (int r = 0; r < 4; ++r) {
            float v = rs[fm][r];
            v += __shfl_xor(v, 1); v += __shfl_xor(v, 2);
            v += __shfl_xor(v, 4); v += __shfl_xor(v, 8);
            int i = iw + fm * 16 + (lane >> 4) * 4 + r;
            if ((lane & 15) == 0 && i < M) atomicAdd(&ws[3 * NM + b_off_w + i], v);
        }
#pragma unroll
    for (int fn = 0; fn < 3; ++fn) {
        float v = cs[fn];
        v += __shfl_xor(v, 16); v += __shfl_xor(v, 32);
        int j = jw + fn * 16 + (lane & 15);
        if ((lane >> 4) == 0 && j < M) atomicAdd(&ws[2 * NM + b_off_w + j], v);
    }
}

// ---------- Kernel 3: sliding-window weighted sum (float4, proven 13 us) ---
__global__ void k_out(const float* __restrict__ x1, const float* __restrict__ x2,
                      const float* __restrict__ ws, float* __restrict__ out) {
    int bid   = blockIdx.x;
    int which = bid & 1;
    int tc    = (bid >> 1) & 7;
    int b     = bid >> 4;
    int d4    = threadIdx.x << 2;
    const float* src  = which ? x2 : x1;
    const float* wgt  = ws + (which ? 3 * NM : 2 * NM) + b * M;
    const float* rows = src + (size_t)b * M * D + d4;
    float* o = out + (size_t)which * OUTHALF + ((size_t)b * T + tc * 32) * D + d4;
    int t0 = tc * 32;
    float4 v0 = *(const float4*)(rows + (size_t)(t0 + 0) * D);
    float4 v1 = *(const float4*)(rows + (size_t)(t0 + 1) * D);
    float4 v2 = *(const float4*)(rows + (size_t)(t0 + 2) * D);
    float s0 = wgt[t0 + 0], s1 = wgt[t0 + 1], s2 = wgt[t0 + 2];
#pragma unroll 4
    for (int tt = 0; tt < 32; ++tt) {
        float4 v3 = *(const float4*)(rows + (size_t)(t0 + tt + 3) * D);
        float s3  = wgt[t0 + tt + 3];
        float4 r;
        r.x = s0 * v0.x + s1 * v1.x + s2 * v2.x + s3 * v3.x;
        r.y = s0 * v0.y + s1 * v1.y + s2 * v2.y + s3 * v3.y;
        r.z = s0 * v0.z + s1 * v1.z + s2 * v2.z + s3 * v3.z;
        r.w = s0 * v0.w + s1 * v1.w + s2 * v2.w + s3 * v3.w;
        *(float4*)(o + (size_t)tt * D) = r;
        v0 = v1; v1 = v2; v2 = v3;
        s0 = s1; s1 = s2; s2 = s3;
    }
}

extern "C" void kernel_launch(void* const* d_in, const int* in_sizes, int n_in,
                              void* d_out, int out_size, void* d_ws, size_t ws_size,
                              hipStream_t stream) {
    const float* x1 = (const float*)d_in[0];
    const float* x2 = (const float*)d_in[1];
    float* out = (float*)d_out;
    float* ws  = (float*)d_ws;

    size_t need = sizeof(float) * 4 * (size_t)NM + sizeof(bf16) * 2 * (size_t)NM * D;
    if (ws_size >= need) {
        bf16* abf = (bf16*)(ws + 4 * (size_t)NM);
        bf16* bbf = abf + (size_t)NM * D;
        k_prep<<<NM / 4, 256, 0, stream>>>(x1, x2, ws, abf, bbf);       // 8288 blocks
        k_pairs_bf<<<BATCH * NTL * NTL, 256, 0, stream>>>(abf, bbf, ws); // 1152 blocks
    } else {
        k_norms<<<NM / 4, 256, 0, stream>>>(x1, x2, ws);
        k_pairs_fb<<<BATCH * NTL * NTL, 256, 0, stream>>>(x1, x2, ws);
    }
    k_out<<<BATCH * 16, 128, 0, stream>>>(x1, x2, ws, out);              // 2048 blocks
}

// Round 12
// 127.595 us; speedup vs baseline: 1.0511x; 1.0511x over previous
//
#include <hip/hip_runtime.h>

#define BATCH 128
#define M 259
#define D 512
#define T 256
#define NM (BATCH * M)          // 33152
#define OUTHALF (BATCH * T * D)

typedef __bf16 bf16;
typedef __bf16 bf16x4 __attribute__((ext_vector_type(4)));
typedef __bf16 bf16x8 __attribute__((ext_vector_type(8)));
typedef float f32x4 __attribute__((ext_vector_type(4)));

// ws float layout: wcol[NM] | wrow[NM]

// ---------------- Kernel 0: zero the accumulators (1 us) -------------------
__global__ void k_zero(float4* __restrict__ ws4) {
    int i = blockIdx.x * 256 + threadIdx.x;
    if (i < (2 * NM + 3) / 4) ws4[i] = make_float4(0.f, 0.f, 0.f, 0.f);
}

// ---------------- Kernel 1: bf16 MFMA pairwise + fragment-path norms -------
// r2-proven staging/swizzle/MFMA structure verbatim (fp32 source, 1-buf,
// 96x96 tile, 4 waves). Norms accumulated from MFMA fragments (LDS->reg
// path, overlaps MFMA pipe) -- NOT on the load path (r4's +54us mistake).
#define BT 96
#define BK 64
#define NTL 3   // 3*96 = 288 >= 259

__launch_bounds__(256)
__global__ void k_pairs(const float* __restrict__ x1, const float* __restrict__ x2,
                        float* __restrict__ ws) {
    __shared__ __align__(16) bf16 As[BT * BK];   // 12 KB
    __shared__ __align__(16) bf16 Bs[BT * BK];   // 12 KB
    __shared__ float na_s[BT];
    __shared__ float nb_s[BT];

    int s   = blockIdx.x;                 // 1152 = 8 * 144, bijective XCD swizzle
    int bid = (s & 7) * 144 + (s >> 3);
    int b   = bid / 9;
    int ti  = (bid % 9) / 3;
    int tj  = bid % 3;
    int i0  = ti * BT, j0 = tj * BT;

    int t    = threadIdx.x;
    int lane = t & 63;
    int w    = t >> 6;
    int wm   = w >> 1, wn = w & 1;
    int iw   = i0 + wm * 48;
    int jw   = j0 + wn * 48;

    const float* Ab = x1 + (size_t)b * M * D;
    const float* Bb = x2 + (size_t)b * M * D;

    // staging: 6 passes of 16 rows x 64 cols per matrix, 1 float4/thread/pass
    const float* pa[6];
    const float* pb[6];
    int c4 = (t & 15) * 4;
#pragma unroll
    for (int p = 0; p < 6; ++p) {
        int ra = min(i0 + p * 16 + (t >> 4), M - 1);
        int rb = min(j0 + p * 16 + (t >> 4), M - 1);
        pa[p] = Ab + (size_t)ra * D + c4;
        pb[p] = Bb + (size_t)rb * D + c4;
    }
    int wslot   = (t & 15) >> 1;
    int wwithin = (t & 1) * 4;
    int wr_off[6];
#pragma unroll
    for (int p = 0; p < 6; ++p) {
        int row = p * 16 + (t >> 4);
        wr_off[p] = row * BK + ((wslot ^ (row & 7)) << 3) + wwithin;
    }

    // fragment read offsets (element units), swizzle-matched (proven)
    int a_off[3][2], b_off[3][2];
#pragma unroll
    for (int fm = 0; fm < 3; ++fm) {
        int rowa = wm * 48 + fm * 16 + (lane & 15);
        int rowb = wn * 48 + fm * 16 + (lane & 15);
#pragma unroll
        for (int kk = 0; kk < 2; ++kk) {
            int sl = kk * 4 + (lane >> 4);
            a_off[fm][kk] = rowa * BK + ((sl ^ (rowa & 7)) << 3);
            b_off[fm][kk] = rowb * BK + ((sl ^ (rowb & 7)) << 3);
        }
    }

    f32x4 acc[3][3];
#pragma unroll
    for (int fm = 0; fm < 3; ++fm)
#pragma unroll
        for (int fn = 0; fn < 3; ++fn) acc[fm][fn] = (f32x4)0.f;

    float nra[3] = {0.f, 0.f, 0.f};   // A-row norm partials (this lane's k-slots)
    float nrb[3] = {0.f, 0.f, 0.f};   // B-row norm partials

    for (int k0 = 0; k0 < D; k0 += BK) {
        float4 va[6], vb[6];
#pragma unroll
        for (int p = 0; p < 6; ++p) {
            va[p] = *(const float4*)(pa[p] + k0);
            vb[p] = *(const float4*)(pb[p] + k0);
        }
        __syncthreads();
#pragma unroll
        for (int p = 0; p < 6; ++p) {
            *(bf16x4*)&As[wr_off[p]] = bf16x4{ (bf16)va[p].x, (bf16)va[p].y, (bf16)va[p].z, (bf16)va[p].w };
            *(bf16x4*)&Bs[wr_off[p]] = bf16x4{ (bf16)vb[p].x, (bf16)vb[p].y, (bf16)vb[p].z, (bf16)vb[p].w };
        }
        __syncthreads();
#pragma unroll
        for (int kk = 0; kk < 2; ++kk) {
            bf16x8 af[3], bfr[3];
#pragma unroll
            for (int fm = 0; fm < 3; ++fm) af[fm]  = *(const bf16x8*)&As[a_off[fm][kk]];
#pragma unroll
            for (int fn = 0; fn < 3; ++fn) bfr[fn] = *(const bf16x8*)&Bs[b_off[fn][kk]];
            // fragment-path norm accumulation (VALU, overlaps MFMA pipe)
#pragma unroll
            for (int f = 0; f < 3; ++f)
#pragma unroll
                for (int e = 0; e < 8; ++e) {
                    float fa = (float)af[f][e];
                    float fb = (float)bfr[f][e];
                    nra[f] = fmaf(fa, fa, nra[f]);
                    nrb[f] = fmaf(fb, fb, nrb[f]);
                }
#pragma unroll
            for (int fm = 0; fm < 3; ++fm)
#pragma unroll
                for (int fn = 0; fn < 3; ++fn)
                    acc[fm][fn] = __builtin_amdgcn_mfma_f32_16x16x32_bf16(
                        af[fm], bfr[fn], acc[fm][fn], 0, 0, 0);
        }
    }

    // reduce norm partials over the 4 k-slot lanes; single-writer to LDS
#pragma unroll
    for (int f = 0; f < 3; ++f) {
        float va_ = nra[f];
        va_ += __shfl_xor(va_, 16); va_ += __shfl_xor(va_, 32);
        float vb_ = nrb[f];
        vb_ += __shfl_xor(vb_, 16); vb_ += __shfl_xor(vb_, 32);
        if (wn == 0 && (lane >> 4) == 0) na_s[wm * 48 + f * 16 + (lane & 15)] = va_;
        if (wm == 0 && (lane >> 4) == 0) nb_s[wn * 48 + f * 16 + (lane & 15)] = vb_;
    }
    __syncthreads();

    // epilogue: A_ij = 1/(1+dist), masked; row/col partial sums (r4-proven idx)
    int b_off_w = b * M;
    float na_[3][4], nb_[3];
#pragma unroll
    for (int fm = 0; fm < 3; ++fm)
#pragma unroll
        for (int r = 0; r < 4; ++r)
            na_[fm][r] = na_s[wm * 48 + fm * 16 + (lane >> 4) * 4 + r];
#pragma unroll
    for (int fn = 0; fn < 3; ++fn)
        nb_[fn] = nb_s[wn * 48 + fn * 16 + (lane & 15)];

    float rs[3][4], cs[3];
#pragma unroll
    for (int fm = 0; fm < 3; ++fm)
#pragma unroll
        for (int r = 0; r < 4; ++r) rs[fm][r] = 0.f;
#pragma unroll
    for (int fn = 0; fn < 3; ++fn) cs[fn] = 0.f;

#pragma unroll
    for (int fm = 0; fm < 3; ++fm) {
#pragma unroll
        for (int fn = 0; fn < 3; ++fn) {
#pragma unroll
            for (int r = 0; r < 4; ++r) {
                int i = iw + fm * 16 + (lane >> 4) * 4 + r;
                int j = jw + fn * 16 + (lane & 15);
                float av = 0.f;
                if (i < M && j < M) {
                    float sq   = na_[fm][r] + nb_[fn] - 2.f * acc[fm][fn][r];
                    float dist = sqrtf(fmaxf(sq, 0.f));
                    av = 1.f / (1.f + dist);
                }
                rs[fm][r] += av;
                cs[fn]    += av;
            }
        }
    }

#pragma unroll
    for (int fm = 0; fm < 3; ++fm)
#pragma unroll
        for (int r = 0; r < 4; ++r) {
            float v = rs[fm][r];
            v += __shfl_xor(v, 1); v += __shfl_xor(v, 2);
            v += __shfl_xor(v, 4); v += __shfl_xor(v, 8);
            int i = iw + fm * 16 + (lane >> 4) * 4 + r;
            if ((lane & 15) == 0 && i < M) atomicAdd(&ws[NM + b_off_w + i], v);  // wrow
        }
#pragma unroll
    for (int fn = 0; fn < 3; ++fn) {
        float v = cs[fn];
        v += __shfl_xor(v, 16); v += __shfl_xor(v, 32);
        int j = jw + fn * 16 + (lane & 15);
        if ((lane >> 4) == 0 && j < M) atomicAdd(&ws[b_off_w + j], v);           // wcol
    }
}

// ---------------- Kernel 2: sliding-window weighted sum (float4, 13 us) ----
__global__ void k_out(const float* __restrict__ x1, const float* __restrict__ x2,
                      const float* __restrict__ ws, float* __restrict__ out) {
    int bid   = blockIdx.x;
    int which = bid & 1;
    int tc    = (bid >> 1) & 7;
    int b     = bid >> 4;
    int d4    = threadIdx.x << 2;
    const float* src  = which ? x2 : x1;
    const float* wgt  = ws + (which ? NM : 0) + b * M;
    const float* rows = src + (size_t)b * M * D + d4;
    float* o = out + (size_t)which * OUTHALF + ((size_t)b * T + tc * 32) * D + d4;
    int t0 = tc * 32;
    float4 v0 = *(const float4*)(rows + (size_t)(t0 + 0) * D);
    float4 v1 = *(const float4*)(rows + (size_t)(t0 + 1) * D);
    float4 v2 = *(const float4*)(rows + (size_t)(t0 + 2) * D);
    float s0 = wgt[t0 + 0], s1 = wgt[t0 + 1], s2 = wgt[t0 + 2];
#pragma unroll 4
    for (int tt = 0; tt < 32; ++tt) {
        float4 v3 = *(const float4*)(rows + (size_t)(t0 + tt + 3) * D);
        float s3  = wgt[t0 + tt + 3];
        float4 r;
        r.x = s0 * v0.x + s1 * v1.x + s2 * v2.x + s3 * v3.x;
        r.y = s0 * v0.y + s1 * v1.y + s2 * v2.y + s3 * v3.y;
        r.z = s0 * v0.z + s1 * v1.z + s2 * v2.z + s3 * v3.z;
        r.w = s0 * v0.w + s1 * v1.w + s2 * v2.w + s3 * v3.w;
        *(float4*)(o + (size_t)tt * D) = r;
        v0 = v1; v1 = v2; v2 = v3;
        s0 = s1; s1 = s2; s2 = s3;
    }
}

extern "C" void kernel_launch(void* const* d_in, const int* in_sizes, int n_in,
                              void* d_out, int out_size, void* d_ws, size_t ws_size,
                              hipStream_t stream) {
    const float* x1 = (const float*)d_in[0];
    const float* x2 = (const float*)d_in[1];
    float* out = (float*)d_out;
    float* ws  = (float*)d_ws;

    k_zero<<<(2 * NM / 4 + 255) / 256, 256, 0, stream>>>((float4*)ws);   // 65 blocks
    k_pairs<<<BATCH * NTL * NTL, 256, 0, stream>>>(x1, x2, ws);          // 1152 blocks
    k_out<<<BATCH * 16, 128, 0, stream>>>(x1, x2, ws, out);              // 2048 blocks
}

// Round 13
// 120.757 us; speedup vs baseline: 1.1106x; 1.0566x over previous
//
#include <hip/hip_runtime.h>

#define BATCH 128
#define M 259
#define D 512
#define T 256
#define NM (BATCH * M)          // 33152
#define OUTHALF (BATCH * T * D)

typedef __bf16 bf16;
typedef __bf16 bf16x4 __attribute__((ext_vector_type(4)));
typedef __bf16 bf16x8 __attribute__((ext_vector_type(8)));
typedef float f32x4 __attribute__((ext_vector_type(4)));

// ws float layout: na[NM] | nb[NM] | wcol[NM] | wrow[NM]

// ---------------- Kernel 1: norms + zero accumulators (r2 verbatim) --------
__global__ void k_norms(const float* __restrict__ x1, const float* __restrict__ x2,
                        float* __restrict__ ws) {
    int row  = blockIdx.x * 4 + (threadIdx.x >> 6);
    int lane = threadIdx.x & 63;
    if (row >= NM) return;
    const float4* p1 = (const float4*)(x1 + (size_t)row * D);
    const float4* p2 = (const float4*)(x2 + (size_t)row * D);
    float s1 = 0.f, s2 = 0.f;
#pragma unroll
    for (int q = 0; q < 2; ++q) {
        float4 v = p1[lane + q * 64];
        s1 += v.x * v.x + v.y * v.y + v.z * v.z + v.w * v.w;
        float4 u = p2[lane + q * 64];
        s2 += u.x * u.x + u.y * u.y + u.z * u.z + u.w * u.w;
    }
#pragma unroll
    for (int off = 32; off > 0; off >>= 1) {
        s1 += __shfl_xor(s1, off);
        s2 += __shfl_xor(s2, off);
    }
    if (lane == 0) {
        ws[row]          = s1;
        ws[NM + row]     = s2;
        ws[2 * NM + row] = 0.f;  // wcol accumulator
        ws[3 * NM + row] = 0.f;  // wrow accumulator
    }
}

// ---------------- Kernel 2: bf16 MFMA pairwise (r2 verbatim, 1-buf) --------
#define BT 96
#define BK 64
#define NTL 3   // 3*96 = 288 >= 259

__launch_bounds__(256)
__global__ void k_pairs(const float* __restrict__ x1, const float* __restrict__ x2,
                        float* __restrict__ ws) {
    __shared__ __align__(16) bf16 As[BT * BK];   // 12 KB
    __shared__ __align__(16) bf16 Bs[BT * BK];   // 12 KB

    int s   = blockIdx.x;                 // 1152 = 8 * 144, bijective XCD swizzle
    int bid = (s & 7) * 144 + (s >> 3);
    int b   = bid / 9;
    int ti  = (bid % 9) / 3;
    int tj  = bid % 3;
    int i0  = ti * BT, j0 = tj * BT;

    int t    = threadIdx.x;
    int lane = t & 63;
    int w    = t >> 6;
    int wm   = w >> 1, wn = w & 1;
    int iw   = i0 + wm * 48;
    int jw   = j0 + wn * 48;

    const float* Ab = x1 + (size_t)b * M * D;
    const float* Bb = x2 + (size_t)b * M * D;

    // staging: 6 passes of 16 rows x 64 cols per matrix, 1 float4/thread/pass
    const float* pa[6];
    const float* pb[6];
    int c4 = (t & 15) * 4;
#pragma unroll
    for (int p = 0; p < 6; ++p) {
        int ra = min(i0 + p * 16 + (t >> 4), M - 1);
        int rb = min(j0 + p * 16 + (t >> 4), M - 1);
        pa[p] = Ab + (size_t)ra * D + c4;
        pb[p] = Bb + (size_t)rb * D + c4;
    }
    int wslot   = (t & 15) >> 1;
    int wwithin = (t & 1) * 4;
    int wr_off[6];
#pragma unroll
    for (int p = 0; p < 6; ++p) {
        int row = p * 16 + (t >> 4);
        wr_off[p] = row * BK + ((wslot ^ (row & 7)) << 3) + wwithin;
    }

    // fragment read offsets (element units), swizzle-matched
    int a_off[3][2], b_off[3][2];
#pragma unroll
    for (int fm = 0; fm < 3; ++fm) {
        int rowa = wm * 48 + fm * 16 + (lane & 15);
        int rowb = wn * 48 + fm * 16 + (lane & 15);
#pragma unroll
        for (int kk = 0; kk < 2; ++kk) {
            int sl = kk * 4 + (lane >> 4);
            a_off[fm][kk] = rowa * BK + ((sl ^ (rowa & 7)) << 3);
            b_off[fm][kk] = rowb * BK + ((sl ^ (rowb & 7)) << 3);
        }
    }

    f32x4 acc[3][3];
#pragma unroll
    for (int fm = 0; fm < 3; ++fm)
#pragma unroll
        for (int fn = 0; fn < 3; ++fn) acc[fm][fn] = (f32x4)0.f;

    for (int k0 = 0; k0 < D; k0 += BK) {
        float4 va[6], vb[6];
#pragma unroll
        for (int p = 0; p < 6; ++p) {
            va[p] = *(const float4*)(pa[p] + k0);
            vb[p] = *(const float4*)(pb[p] + k0);
        }
        __syncthreads();
#pragma unroll
        for (int p = 0; p < 6; ++p) {
            *(bf16x4*)&As[wr_off[p]] = bf16x4{ (bf16)va[p].x, (bf16)va[p].y, (bf16)va[p].z, (bf16)va[p].w };
            *(bf16x4*)&Bs[wr_off[p]] = bf16x4{ (bf16)vb[p].x, (bf16)vb[p].y, (bf16)vb[p].z, (bf16)vb[p].w };
        }
        __syncthreads();
#pragma unroll
        for (int kk = 0; kk < 2; ++kk) {
            bf16x8 af[3], bfr[3];
#pragma unroll
            for (int fm = 0; fm < 3; ++fm) af[fm]  = *(const bf16x8*)&As[a_off[fm][kk]];
#pragma unroll
            for (int fn = 0; fn < 3; ++fn) bfr[fn] = *(const bf16x8*)&Bs[b_off[fn][kk]];
#pragma unroll
            for (int fm = 0; fm < 3; ++fm)
#pragma unroll
                for (int fn = 0; fn < 3; ++fn)
                    acc[fm][fn] = __builtin_amdgcn_mfma_f32_16x16x32_bf16(
                        af[fm], bfr[fn], acc[fm][fn], 0, 0, 0);
        }
    }

    // epilogue: A_ij = 1/(1+dist), masked; row/col partial sums
    int b_off_w = b * M;
    float na_[3][4], nb_[3];
#pragma unroll
    for (int fm = 0; fm < 3; ++fm)
#pragma unroll
        for (int r = 0; r < 4; ++r) {
            int i = iw + fm * 16 + (lane >> 4) * 4 + r;
            na_[fm][r] = (i < M) ? ws[b_off_w + i] : 0.f;
        }
#pragma unroll
    for (int fn = 0; fn < 3; ++fn) {
        int j = jw + fn * 16 + (lane & 15);
        nb_[fn] = (j < M) ? ws[NM + b_off_w + j] : 0.f;
    }

    float rs[3][4], cs[3];
#pragma unroll
    for (int fm = 0; fm < 3; ++fm)
#pragma unroll
        for (int r = 0; r < 4; ++r) rs[fm][r] = 0.f;
#pragma unroll
    for (int fn = 0; fn < 3; ++fn) cs[fn] = 0.f;

#pragma unroll
    for (int fm = 0; fm < 3; ++fm) {
#pragma unroll
        for (int fn = 0; fn < 3; ++fn) {
#pragma unroll
            for (int r = 0; r < 4; ++r) {
                int i = iw + fm * 16 + (lane >> 4) * 4 + r;
                int j = jw + fn * 16 + (lane & 15);
                float av = 0.f;
                if (i < M && j < M) {
                    float sq   = na_[fm][r] + nb_[fn] - 2.f * acc[fm][fn][r];
                    float dist = sqrtf(fmaxf(sq, 0.f));
                    av = 1.f / (1.f + dist);
                }
                rs[fm][r] += av;
                cs[fn]    += av;
            }
        }
    }

#pragma unroll
    for (int fm = 0; fm < 3; ++fm)
#pragma unroll
        for (int r = 0; r < 4; ++r) {
            float v = rs[fm][r];
            v += __shfl_xor(v, 1); v += __shfl_xor(v, 2);
            v += __shfl_xor(v, 4); v += __shfl_xor(v, 8);
            int i = iw + fm * 16 + (lane >> 4) * 4 + r;
            if ((lane & 15) == 0 && i < M) atomicAdd(&ws[3 * NM + b_off_w + i], v);  // wrow
        }
#pragma unroll
    for (int fn = 0; fn < 3; ++fn) {
        float v = cs[fn];
        v += __shfl_xor(v, 16); v += __shfl_xor(v, 32);
        int j = jw + fn * 16 + (lane & 15);
        if ((lane >> 4) == 0 && j < M) atomicAdd(&ws[2 * NM + b_off_w + j], v);      // wcol
    }
}

// ---------------- Kernel 3: sliding-window weighted sum (float4, r6) -------
__global__ void k_out(const float* __restrict__ x1, const float* __restrict__ x2,
                      const float* __restrict__ ws, float* __restrict__ out) {
    int bid   = blockIdx.x;
    int which = bid & 1;
    int tc    = (bid >> 1) & 7;
    int b     = bid >> 4;
    int d4    = threadIdx.x << 2;
    const float* src  = which ? x2 : x1;
    const float* wgt  = ws + (which ? 3 * NM : 2 * NM) + b * M;
    const float* rows = src + (size_t)b * M * D + d4;
    float* o = out + (size_t)which * OUTHALF + ((size_t)b * T + tc * 32) * D + d4;
    int t0 = tc * 32;
    float4 v0 = *(const float4*)(rows + (size_t)(t0 + 0) * D);
    float4 v1 = *(const float4*)(rows + (size_t)(t0 + 1) * D);
    float4 v2 = *(const float4*)(rows + (size_t)(t0 + 2) * D);
    float s0 = wgt[t0 + 0], s1 = wgt[t0 + 1], s2 = wgt[t0 + 2];
#pragma unroll 4
    for (int tt = 0; tt < 32; ++tt) {
        float4 v3 = *(const float4*)(rows + (size_t)(t0 + tt + 3) * D);
        float s3  = wgt[t0 + tt + 3];
        float4 r;
        r.x = s0 * v0.x + s1 * v1.x + s2 * v2.x + s3 * v3.x;
        r.y = s0 * v0.y + s1 * v1.y + s2 * v2.y + s3 * v3.y;
        r.z = s0 * v0.z + s1 * v1.z + s2 * v2.z + s3 * v3.z;
        r.w = s0 * v0.w + s1 * v1.w + s2 * v2.w + s3 * v3.w;
        *(float4*)(o + (size_t)tt * D) = r;
        v0 = v1; v1 = v2; v2 = v3;
        s0 = s1; s1 = s2; s2 = s3;
    }
}

extern "C" void kernel_launch(void* const* d_in, const int* in_sizes, int n_in,
                              void* d_out, int out_size, void* d_ws, size_t ws_size,
                              hipStream_t stream) {
    const float* x1 = (const float*)d_in[0];
    const float* x2 = (const float*)d_in[1];
    float* out = (float*)d_out;
    float* ws  = (float*)d_ws;

    k_norms<<<NM / 4, 256, 0, stream>>>(x1, x2, ws);        // 8288 blocks
    k_pairs<<<BATCH * NTL * NTL, 256, 0, stream>>>(x1, x2, ws);  // 1152 blocks
    k_out<<<BATCH * 16, 128, 0, stream>>>(x1, x2, ws, out); // 2048 blocks
}